// Round 3
// baseline (20192.390 us; speedup 1.0000x reference)
//
#include <hip/hip_runtime.h>
#include <hip/hip_bf16.h>

// ---------------------------------------------------------------------------
// LSTMTagger: char-LSTM (4096x16, H=128) -> word-LSTM (serial 4096, H=512)
//             -> linear(64) + log_softmax.
// Wire dtype of float tensors detected at runtime (bf16 vs f32) from char_emb
// bit patterns; kernels dual-path on device flag ws[0]: 1 = bf16, 0 = f32.
//
// Word LSTM (the serial wall): 32 WGs x 1024 threads. Wave w of WG wg owns
// h-slot wg*16+w; lane (g,kk) holds Whh[g*512+slot][kk*32..+32) in registers.
// Wave 0 of each WG is the only fabric poller; it stages h into padded,
// double-buffered LDS and releases an LDS flag the compute waves spin on.
// Each WG's 16 h-slots live in ONE 64B line of h_hist (no writer sharing).
// h_hist dwords double as ready flags via 0xFF sentinel (h in (-1,1), so
// 0xFFFFFFFF = -NaN is unreachable).
// ---------------------------------------------------------------------------

#define OFF_FLAG  0
#define OFF_CEMB  16
#define OFF_CWIH  8208
#define OFF_CBIH  40976
#define OFF_CBHH  41488
#define OFF_CWHH  42000
#define OFF_BIH   107536
#define OFF_BHH   109584
#define OFF_W1T   111632
#define OFF_CGE   144400
#define OFF_CH    209936
#define OFF_XP2   734224
#define OFF_HH    4928528

#define SENT 0xFFFFFFFFu

__device__ __forceinline__ float sigf(float x) { return 1.0f / (1.0f + __expf(-x)); }
__device__ __forceinline__ float tanh_f(float x) { return 2.0f * sigf(2.0f * x) - 1.0f; }
__device__ __forceinline__ float b2f_lo(unsigned u) { return __uint_as_float(u << 16); }
__device__ __forceinline__ float b2f_hi(unsigned u) { return __uint_as_float(u & 0xFFFF0000u); }

// ---- D0: dtype detect (see Round-2 notes). -------------------------------
__global__ void detect_kernel(const unsigned* __restrict__ w, int* __restrict__ flagp) {
    unsigned v = w[threadIdx.x];
    unsigned e = (v >> 7) & 0xFF;
    int inr = (e >= 100 && e <= 140) ? 1 : 0;
    unsigned long long m = __ballot(inr);
    if (threadIdx.x == 0) flagp[0] = (__popcll(m) >= 56) ? 1 : 0;
}

// ---- K0: (bf16|f32) -> f32 convert ---------------------------------------
__global__ void convf_kernel(const void* __restrict__ s, float* __restrict__ d,
                             int n, const int* __restrict__ flagp) {
    int i = blockIdx.x * 256 + threadIdx.x;
    if (i >= n) return;
    d[i] = flagp[0] ? __bfloat162float(((const __hip_bfloat16*)s)[i])
                    : ((const float*)s)[i];
}

// ---- K0b: W1 (64x512) -> W1T (512x64) f32 --------------------------------
__global__ void w1t_kernel(const void* __restrict__ W1, float* __restrict__ W1T,
                           const int* __restrict__ flagp) {
    int i = blockIdx.x * 256 + threadIdx.x;   // 0..32767
    int j = i & 63, k = i >> 6;
    W1T[i] = flagp[0] ? __bfloat162float(((const __hip_bfloat16*)W1)[j * 512 + k])
                      : ((const float*)W1)[j * 512 + k];
}

// ---- K1: char gate table: cge[c][j] = emb[c] . cWih[j] + cbih[j] + cbhh[j]
__global__ void __launch_bounds__(256) cge_kernel(
    const float* __restrict__ cemb, const float* __restrict__ cWih,
    const float* __restrict__ cbih, const float* __restrict__ cbhh,
    float* __restrict__ cge)
{
    __shared__ float xe[64];
    int c = blockIdx.x, tid = threadIdx.x;
    if (tid < 64) xe[tid] = cemb[c * 64 + tid];
    __syncthreads();
#pragma unroll
    for (int rep = 0; rep < 2; ++rep) {
        int j = rep * 256 + tid;
        float acc = cbih[j] + cbhh[j];
#pragma unroll 8
        for (int k = 0; k < 64; ++k)
            acc += xe[k] * cWih[j * 64 + k];
        cge[c * 512 + j] = acc;
    }
}

// ---- K2: char LSTM. 16 words/block; thread (wl,sl) owns word wl,
//          h-slots sl*8..sl*8+8. 16 steps with length masking. -------------
__global__ void __launch_bounds__(256) char_lstm_kernel(
    const float* __restrict__ cge, const float* __restrict__ Whh,
    const int* __restrict__ chars, const int* __restrict__ lens,
    float* __restrict__ char_h)
{
    __shared__ float hls[16][128];
    int tid = threadIdx.x;
    int wl = tid >> 4, sl = tid & 15;
    int w = blockIdx.x * 16 + wl;
    int len = lens[w];
    const int* cw = chars + w * 16;
    float c[8];
#pragma unroll
    for (int q = 0; q < 8; ++q) { c[q] = 0.0f; hls[wl][sl * 8 + q] = 0.0f; }

    for (int t = 0; t < 16; ++t) {
        __syncthreads();
        int ch = cw[t];
        const float* xg = cge + ch * 512;
        float acc[4][8];
#pragma unroll
        for (int g = 0; g < 4; ++g)
#pragma unroll
            for (int q = 0; q < 8; ++q)
                acc[g][q] = xg[g * 128 + sl * 8 + q];

        const float4* h4 = (const float4*)hls[wl];
#pragma unroll
        for (int g = 0; g < 4; ++g) {
            const float4* wbase = ((const float4*)Whh) + (g * 128 + sl * 8) * 32;
            for (int k4 = 0; k4 < 32; ++k4) {
                float4 hv = h4[k4];
#pragma unroll
                for (int q = 0; q < 8; ++q) {
                    float4 wv = wbase[q * 32 + k4];
                    acc[g][q] += wv.x * hv.x + wv.y * hv.y + wv.z * hv.z + wv.w * hv.w;
                }
            }
        }
        __syncthreads();
        if (t < len) {
#pragma unroll
            for (int q = 0; q < 8; ++q) {
                float iv = sigf(acc[0][q]);
                float fv = sigf(acc[1][q]);
                float gv = tanh_f(acc[2][q]);
                float ov = sigf(acc[3][q]);
                c[q] = fv * c[q] + iv * gv;
                hls[wl][sl * 8 + q] = ov * tanh_f(c[q]);
            }
        }
    }
    __syncthreads();
#pragma unroll
    for (int q = 0; q < 8; ++q)
        char_h[w * 128 + sl * 8 + q] = hls[wl][sl * 8 + q];
}

// ---- K3: word x-part gates (bf16 out). -----------------------------------
__global__ void __launch_bounds__(256) xp2_kernel(
    const void* __restrict__ wemb, const int* __restrict__ x,
    const float* __restrict__ char_h, const void* __restrict__ Wraw,
    const float* __restrict__ bih, const float* __restrict__ bhh,
    __hip_bfloat16* __restrict__ xp2, const int* __restrict__ flagp)
{
    __shared__ float feat[16][384];
    int flag = flagp[0];
    int tid = threadIdx.x, tl = tid >> 4, sl = tid & 15;
    int t = blockIdx.x * 16 + tl;
    int xw = x[t];
    for (int idx = sl; idx < 384; idx += 16) {
        float v;
        if (idx < 256)
            v = flag ? __bfloat162float(((const __hip_bfloat16*)wemb)[(size_t)xw * 256 + idx])
                     : ((const float*)wemb)[(size_t)xw * 256 + idx];
        else
            v = char_h[t * 128 + (idx - 256)];
        feat[tl][idx] = v;
    }
    __syncthreads();

    const float4* f4 = (const float4*)feat[tl];
    for (int rb = 0; rb < 4; ++rb) {
        int r0 = rb * 512 + sl * 32;
        for (int qc = 0; qc < 4; ++qc) {
            int rr = r0 + qc * 8;
            float acc[8];
#pragma unroll
            for (int q = 0; q < 8; ++q)
                acc[q] = bih[rr + q] + bhh[rr + q];
            if (!flag) {
                const float4* wb = ((const float4*)Wraw) + (size_t)rr * 96;
                for (int k4 = 0; k4 < 96; ++k4) {
                    float4 fv = f4[k4];
#pragma unroll
                    for (int q = 0; q < 8; ++q) {
                        float4 wv = wb[q * 96 + k4];
                        acc[q] += wv.x * fv.x + wv.y * fv.y + wv.z * fv.z + wv.w * fv.w;
                    }
                }
            } else {
                const uint2* wb = ((const uint2*)Wraw) + (size_t)rr * 96;
                for (int k4 = 0; k4 < 96; ++k4) {
                    float4 fv = f4[k4];
#pragma unroll
                    for (int q = 0; q < 8; ++q) {
                        uint2 wv = wb[q * 96 + k4];
                        acc[q] += b2f_lo(wv.x) * fv.x + b2f_hi(wv.x) * fv.y
                                + b2f_lo(wv.y) * fv.z + b2f_hi(wv.y) * fv.w;
                    }
                }
            }
#pragma unroll
            for (int q = 0; q < 8; ++q)
                xp2[(size_t)t * 2048 + rr + q] = __float2bfloat16(acc[q]);
        }
    }
}

// ---- K5: serial word LSTM (latency-optimized). ---------------------------
// 32 WGs x 1024 thr (16 waves). Wave w owns slot wg*16+w. Lane (g,kk):
// 32 Whh f32 in regs. Wave 0 = sole fabric poller; LDS flag + padded
// double-buffered h stage for the compute waves.
__global__ void __launch_bounds__(1024, 4) word_lstm_kernel(
    const __hip_bfloat16* __restrict__ xp2, const void* __restrict__ Whh_raw,
    float* __restrict__ h_hist, const int* __restrict__ flagp)
{
    __shared__ float hpad[2][576];   // 16 chunks x (32 + 4 pad)
    __shared__ int step_flag;
    int flag = flagp[0];
    int wg = blockIdx.x;
    int tid = threadIdx.x;
    int wave = tid >> 6, lane = tid & 63;
    int g = lane >> 4, kk = lane & 15;
    int slot = wg * 16 + wave;
    int grow = g * 512 + slot;

    // weights: Whh[grow][kk*32 .. +31] -> 8 float4 in regs
    float4 wreg[8];
    if (!flag) {
        const float4* wr = (const float4*)((const float*)Whh_raw + (size_t)grow * 512 + kk * 32);
#pragma unroll
        for (int i = 0; i < 8; ++i) wreg[i] = wr[i];
    } else {
        const uint2* wr = (const uint2*)((const unsigned short*)Whh_raw + (size_t)grow * 512 + kk * 32);
#pragma unroll
        for (int i = 0; i < 8; ++i) {
            uint2 u = wr[i];
            wreg[i] = make_float4(b2f_lo(u.x), b2f_hi(u.x), b2f_lo(u.y), b2f_hi(u.y));
        }
    }

    for (int i = tid; i < 576; i += 1024) hpad[0][i] = 0.0f;   // h_{-1} = 0
    if (tid == 0) step_flag = 0;                                // buffer 0 ready for t=0
    __syncthreads();

    unsigned* hview = (unsigned*)h_hist;
    float c = 0.0f;

    for (int t = 0; t < 4096; ++t) {
        // h-independent: issue before the wait so latency hides under the spin
        float xv = __bfloat162float(xp2[(size_t)t * 2048 + grow]);

        // wait for hpad[t&1] = h_{t-1}  (LDS spin, no fabric traffic)
        unsigned ls = 0;
        while (__hip_atomic_load(&step_flag, __ATOMIC_ACQUIRE,
                                 __HIP_MEMORY_SCOPE_WORKGROUP) < t) {
            if (++ls > (1u << 24)) break;   // anti-hang
        }

        const float4* h4 = (const float4*)(&hpad[t & 1][kk * 36]);
        float acc = 0.0f;
#pragma unroll
        for (int i = 0; i < 8; ++i) {
            float4 hv = h4[i];
            acc += wreg[i].x * hv.x + wreg[i].y * hv.y +
                   wreg[i].z * hv.z + wreg[i].w * hv.w;
        }
        acc += __shfl_xor(acc, 1);
        acc += __shfl_xor(acc, 2);
        acc += __shfl_xor(acc, 4);
        acc += __shfl_xor(acc, 8);
        float gvt = acc + xv;

        float iv = __shfl(gvt, kk);
        float fv = __shfl(gvt, 16 + kk);
        float gg = __shfl(gvt, 32 + kk);
        float ov = __shfl(gvt, 48 + kk);
        c = sigf(fv) * c + sigf(iv) * tanh_f(gg);
        float h = sigf(ov) * tanh_f(c);

        if (lane == 0)
            __hip_atomic_store(hview + (size_t)t * 512 + slot, __float_as_uint(h),
                               __ATOMIC_RELAXED, __HIP_MEMORY_SCOPE_AGENT);

        if (wave == 0 && t < 4095) {
            // poll all 512 slots of h_t; stage into the other LDS buffer
            const unsigned* src = hview + (size_t)t * 512 + lane * 8;
            unsigned v[8];
            unsigned spins = 0;
            bool bail = false;
            for (;;) {
#pragma unroll
                for (int i = 0; i < 8; ++i)
                    v[i] = __hip_atomic_load(src + i, __ATOMIC_RELAXED,
                                             __HIP_MEMORY_SCOPE_AGENT);
                int ok = 1;
#pragma unroll
                for (int i = 0; i < 8; ++i) ok &= (v[i] != SENT);
                if (__all(ok)) break;
                if (++spins > (1u << 22)) { bail = true; break; }
            }
            if (bail) {
#pragma unroll
                for (int i = 0; i < 8; ++i) v[i] = __float_as_uint(12345.0f);
            }
            // dword d=lane*8+i -> hpad[chunk d>>5][(d&31)], chunk stride 36
            float* dst = &hpad[(t + 1) & 1][(lane >> 2) * 36 + (lane & 3) * 8];
            ((float4*)dst)[0] = make_float4(__uint_as_float(v[0]), __uint_as_float(v[1]),
                                            __uint_as_float(v[2]), __uint_as_float(v[3]));
            ((float4*)dst)[1] = make_float4(__uint_as_float(v[4]), __uint_as_float(v[5]),
                                            __uint_as_float(v[6]), __uint_as_float(v[7]));
            __hip_atomic_store(&step_flag, t + 1, __ATOMIC_RELEASE,
                               __HIP_MEMORY_SCOPE_WORKGROUP);
        }
    }
}

// ---- K6: logits + log_softmax. one wave per timestep. --------------------
__global__ void __launch_bounds__(64) out_kernel(
    const float* __restrict__ h_hist, const float* __restrict__ W1T,
    const void* __restrict__ b1raw, void* __restrict__ out,
    const int* __restrict__ flagp)
{
    __shared__ float hb[512];
    int flag = flagp[0];
    int t = blockIdx.x, j = threadIdx.x;
    const float4* src = (const float4*)(h_hist + (size_t)t * 512);
    ((float4*)hb)[j * 2] = src[j * 2];
    ((float4*)hb)[j * 2 + 1] = src[j * 2 + 1];
    __syncthreads();

    float acc = flag ? __bfloat162float(((const __hip_bfloat16*)b1raw)[j])
                     : ((const float*)b1raw)[j];
#pragma unroll 8
    for (int k = 0; k < 512; ++k)
        acc += hb[k] * W1T[k * 64 + j];

    float m = acc;
#pragma unroll
    for (int o = 32; o; o >>= 1) m = fmaxf(m, __shfl_xor(m, o));
    float e = __expf(acc - m);
    float s = e;
#pragma unroll
    for (int o = 32; o; o >>= 1) s += __shfl_xor(s, o);
    float r = acc - m - __logf(s);
    if (flag) ((__hip_bfloat16*)out)[t * 64 + j] = __float2bfloat16(r);
    else      ((float*)out)[t * 64 + j] = r;
}

extern "C" void kernel_launch(void* const* d_in, const int* in_sizes, int n_in,
                              void* d_out, int out_size, void* d_ws, size_t ws_size,
                              hipStream_t stream)
{
    (void)in_sizes; (void)n_in; (void)out_size; (void)ws_size;
    const void* char_emb = d_in[0];
    const void* char_Wih = d_in[1];
    const void* char_Whh = d_in[2];
    const void* char_bih = d_in[3];
    const void* char_bhh = d_in[4];
    const void* word_emb = d_in[5];
    const void* Wih      = d_in[6];
    const void* Whh      = d_in[7];
    const void* bih      = d_in[8];
    const void* bhh      = d_in[9];
    const void* W1       = d_in[10];
    const void* b1       = d_in[11];
    const int* x     = (const int*)d_in[12];
    const int* chars = (const int*)d_in[13];
    const int* lens  = (const int*)d_in[14];

    float* ws    = (float*)d_ws;
    int*   flagp = (int*)(ws + OFF_FLAG);
    float* cembf = ws + OFF_CEMB;
    float* cWihf = ws + OFF_CWIH;
    float* cbihf = ws + OFF_CBIH;
    float* cbhhf = ws + OFF_CBHH;
    float* cWhhf = ws + OFF_CWHH;
    float* bihf  = ws + OFF_BIH;
    float* bhhf  = ws + OFF_BHH;
    float* W1T   = ws + OFF_W1T;
    float* cge   = ws + OFF_CGE;
    float* charh = ws + OFF_CH;
    __hip_bfloat16* xp2 = (__hip_bfloat16*)(ws + OFF_XP2);
    float* hh    = ws + OFF_HH;

    // sentinel-fill h history (data-as-flag for the serial kernel)
    hipMemsetAsync(hh, 0xFF, (size_t)4096 * 512 * 4, stream);

    detect_kernel<<<1, 64, 0, stream>>>((const unsigned*)char_emb, flagp);

    convf_kernel<<<(8192 + 255) / 256, 256, 0, stream>>>(char_emb, cembf, 8192, flagp);
    convf_kernel<<<(32768 + 255) / 256, 256, 0, stream>>>(char_Wih, cWihf, 32768, flagp);
    convf_kernel<<<2, 256, 0, stream>>>(char_bih, cbihf, 512, flagp);
    convf_kernel<<<2, 256, 0, stream>>>(char_bhh, cbhhf, 512, flagp);
    convf_kernel<<<(65536 + 255) / 256, 256, 0, stream>>>(char_Whh, cWhhf, 65536, flagp);
    convf_kernel<<<8, 256, 0, stream>>>(bih, bihf, 2048, flagp);
    convf_kernel<<<8, 256, 0, stream>>>(bhh, bhhf, 2048, flagp);
    w1t_kernel<<<128, 256, 0, stream>>>(W1, W1T, flagp);

    cge_kernel<<<128, 256, 0, stream>>>(cembf, cWihf, cbihf, cbhhf, cge);
    char_lstm_kernel<<<256, 256, 0, stream>>>(cge, cWhhf, chars, lens, charh);
    xp2_kernel<<<256, 256, 0, stream>>>(word_emb, x, charh, Wih, bihf, bhhf, xp2, flagp);
    word_lstm_kernel<<<32, 1024, 0, stream>>>(xp2, Whh, hh, flagp);
    out_kernel<<<4096, 64, 0, stream>>>(hh, W1T, b1, d_out, flagp);
}

// Round 4
// 13496.704 us; speedup vs baseline: 1.4961x; 1.4961x over previous
//
#include <hip/hip_runtime.h>
#include <hip/hip_bf16.h>

// ---------------------------------------------------------------------------
// LSTMTagger: char-LSTM (4096x16, H=128) -> word-LSTM (serial 4096, H=512)
//             -> linear(64) + log_softmax.
// Wire dtype of float tensors detected at runtime (bf16 vs f32); kernels
// dual-path on device flag ws[0]: 1 = bf16, 0 = f32.
//
// Word LSTM: 32 WGs x 1024 threads (16 waves). Wave w of WG wg owns h-slot
// wg*16+w; lane (g,kk) holds Whh[g*512+slot][kk*32..+32) in registers.
// Per step: waves deposit h into LDS hout[16] -> barrier -> wave 0 issues ONE
// coalesced 64B line store (16 lanes, single instruction => single ownership
// acquisition -- round 3's 16 separate one-lane stores to the same line were
// the 4 us/step critical path) -> wave 0 polls the 31 REMOTE lines only,
// stages h into padded double-buffered LDS, releases an LDS flag the compute
// waves spin on. h_hist dwords double as ready flags via 0xFF sentinel
// (h in (-1,1), 0xFFFFFFFF = -NaN unreachable).
// ---------------------------------------------------------------------------

#define OFF_FLAG  0
#define OFF_CEMB  16
#define OFF_CWIH  8208
#define OFF_CBIH  40976
#define OFF_CBHH  41488
#define OFF_CWHH  42000
#define OFF_BIH   107536
#define OFF_BHH   109584
#define OFF_W1T   111632
#define OFF_CGE   144400
#define OFF_CH    209936
#define OFF_XP2   734224
#define OFF_HH    4928528

#define SENT 0xFFFFFFFFu

__device__ __forceinline__ float sigf(float x) { return 1.0f / (1.0f + __expf(-x)); }
__device__ __forceinline__ float tanh_f(float x) { return 2.0f * sigf(2.0f * x) - 1.0f; }
__device__ __forceinline__ float b2f_lo(unsigned u) { return __uint_as_float(u << 16); }
__device__ __forceinline__ float b2f_hi(unsigned u) { return __uint_as_float(u & 0xFFFF0000u); }

// ---- D0: dtype detect. ---------------------------------------------------
__global__ void detect_kernel(const unsigned* __restrict__ w, int* __restrict__ flagp) {
    unsigned v = w[threadIdx.x];
    unsigned e = (v >> 7) & 0xFF;
    int inr = (e >= 100 && e <= 140) ? 1 : 0;
    unsigned long long m = __ballot(inr);
    if (threadIdx.x == 0) flagp[0] = (__popcll(m) >= 56) ? 1 : 0;
}

// ---- K0: (bf16|f32) -> f32 convert ---------------------------------------
__global__ void convf_kernel(const void* __restrict__ s, float* __restrict__ d,
                             int n, const int* __restrict__ flagp) {
    int i = blockIdx.x * 256 + threadIdx.x;
    if (i >= n) return;
    d[i] = flagp[0] ? __bfloat162float(((const __hip_bfloat16*)s)[i])
                    : ((const float*)s)[i];
}

// ---- K0b: W1 (64x512) -> W1T (512x64) f32 --------------------------------
__global__ void w1t_kernel(const void* __restrict__ W1, float* __restrict__ W1T,
                           const int* __restrict__ flagp) {
    int i = blockIdx.x * 256 + threadIdx.x;   // 0..32767
    int j = i & 63, k = i >> 6;
    W1T[i] = flagp[0] ? __bfloat162float(((const __hip_bfloat16*)W1)[j * 512 + k])
                      : ((const float*)W1)[j * 512 + k];
}

// ---- K1: char gate table ------------------------------------------------
__global__ void __launch_bounds__(256) cge_kernel(
    const float* __restrict__ cemb, const float* __restrict__ cWih,
    const float* __restrict__ cbih, const float* __restrict__ cbhh,
    float* __restrict__ cge)
{
    __shared__ float xe[64];
    int c = blockIdx.x, tid = threadIdx.x;
    if (tid < 64) xe[tid] = cemb[c * 64 + tid];
    __syncthreads();
#pragma unroll
    for (int rep = 0; rep < 2; ++rep) {
        int j = rep * 256 + tid;
        float acc = cbih[j] + cbhh[j];
#pragma unroll 8
        for (int k = 0; k < 64; ++k)
            acc += xe[k] * cWih[j * 64 + k];
        cge[c * 512 + j] = acc;
    }
}

// ---- K2: char LSTM -------------------------------------------------------
__global__ void __launch_bounds__(256) char_lstm_kernel(
    const float* __restrict__ cge, const float* __restrict__ Whh,
    const int* __restrict__ chars, const int* __restrict__ lens,
    float* __restrict__ char_h)
{
    __shared__ float hls[16][128];
    int tid = threadIdx.x;
    int wl = tid >> 4, sl = tid & 15;
    int w = blockIdx.x * 16 + wl;
    int len = lens[w];
    const int* cw = chars + w * 16;
    float c[8];
#pragma unroll
    for (int q = 0; q < 8; ++q) { c[q] = 0.0f; hls[wl][sl * 8 + q] = 0.0f; }

    for (int t = 0; t < 16; ++t) {
        __syncthreads();
        int ch = cw[t];
        const float* xg = cge + ch * 512;
        float acc[4][8];
#pragma unroll
        for (int g = 0; g < 4; ++g)
#pragma unroll
            for (int q = 0; q < 8; ++q)
                acc[g][q] = xg[g * 128 + sl * 8 + q];

        const float4* h4 = (const float4*)hls[wl];
#pragma unroll
        for (int g = 0; g < 4; ++g) {
            const float4* wbase = ((const float4*)Whh) + (g * 128 + sl * 8) * 32;
            for (int k4 = 0; k4 < 32; ++k4) {
                float4 hv = h4[k4];
#pragma unroll
                for (int q = 0; q < 8; ++q) {
                    float4 wv = wbase[q * 32 + k4];
                    acc[g][q] += wv.x * hv.x + wv.y * hv.y + wv.z * hv.z + wv.w * hv.w;
                }
            }
        }
        __syncthreads();
        if (t < len) {
#pragma unroll
            for (int q = 0; q < 8; ++q) {
                float iv = sigf(acc[0][q]);
                float fv = sigf(acc[1][q]);
                float gv = tanh_f(acc[2][q]);
                float ov = sigf(acc[3][q]);
                c[q] = fv * c[q] + iv * gv;
                hls[wl][sl * 8 + q] = ov * tanh_f(c[q]);
            }
        }
    }
    __syncthreads();
#pragma unroll
    for (int q = 0; q < 8; ++q)
        char_h[w * 128 + sl * 8 + q] = hls[wl][sl * 8 + q];
}

// ---- K3: word x-part gates (bf16 out) ------------------------------------
__global__ void __launch_bounds__(256) xp2_kernel(
    const void* __restrict__ wemb, const int* __restrict__ x,
    const float* __restrict__ char_h, const void* __restrict__ Wraw,
    const float* __restrict__ bih, const float* __restrict__ bhh,
    __hip_bfloat16* __restrict__ xp2, const int* __restrict__ flagp)
{
    __shared__ float feat[16][384];
    int flag = flagp[0];
    int tid = threadIdx.x, tl = tid >> 4, sl = tid & 15;
    int t = blockIdx.x * 16 + tl;
    int xw = x[t];
    for (int idx = sl; idx < 384; idx += 16) {
        float v;
        if (idx < 256)
            v = flag ? __bfloat162float(((const __hip_bfloat16*)wemb)[(size_t)xw * 256 + idx])
                     : ((const float*)wemb)[(size_t)xw * 256 + idx];
        else
            v = char_h[t * 128 + (idx - 256)];
        feat[tl][idx] = v;
    }
    __syncthreads();

    const float4* f4 = (const float4*)feat[tl];
    for (int rb = 0; rb < 4; ++rb) {
        int r0 = rb * 512 + sl * 32;
        for (int qc = 0; qc < 4; ++qc) {
            int rr = r0 + qc * 8;
            float acc[8];
#pragma unroll
            for (int q = 0; q < 8; ++q)
                acc[q] = bih[rr + q] + bhh[rr + q];
            if (!flag) {
                const float4* wb = ((const float4*)Wraw) + (size_t)rr * 96;
                for (int k4 = 0; k4 < 96; ++k4) {
                    float4 fv = f4[k4];
#pragma unroll
                    for (int q = 0; q < 8; ++q) {
                        float4 wv = wb[q * 96 + k4];
                        acc[q] += wv.x * fv.x + wv.y * fv.y + wv.z * fv.z + wv.w * fv.w;
                    }
                }
            } else {
                const uint2* wb = ((const uint2*)Wraw) + (size_t)rr * 96;
                for (int k4 = 0; k4 < 96; ++k4) {
                    float4 fv = f4[k4];
#pragma unroll
                    for (int q = 0; q < 8; ++q) {
                        uint2 wv = wb[q * 96 + k4];
                        acc[q] += b2f_lo(wv.x) * fv.x + b2f_hi(wv.x) * fv.y
                                + b2f_lo(wv.y) * fv.z + b2f_hi(wv.y) * fv.w;
                    }
                }
            }
#pragma unroll
            for (int q = 0; q < 8; ++q)
                xp2[(size_t)t * 2048 + rr + q] = __float2bfloat16(acc[q]);
        }
    }
}

// ---- K5: serial word LSTM (coalesced-line-store version) -----------------
__global__ void __launch_bounds__(1024, 4) word_lstm_kernel(
    const __hip_bfloat16* __restrict__ xp2, const void* __restrict__ Whh_raw,
    float* __restrict__ h_hist, const int* __restrict__ flagp)
{
    __shared__ float hpad[2][576];   // 16 chunks x (32 + 4 pad)
    __shared__ float hout[16];       // this WG's 16 fresh h values
    __shared__ int step_flag;
    int flag = flagp[0];
    int wg = blockIdx.x;
    int tid = threadIdx.x;
    int wave = tid >> 6, lane = tid & 63;
    int g = lane >> 4, kk = lane & 15;
    int slot = wg * 16 + wave;
    int grow = g * 512 + slot;

    // weights: Whh[grow][kk*32 .. +31] -> 8 float4 in regs
    float4 wreg[8];
    if (!flag) {
        const float4* wr = (const float4*)((const float*)Whh_raw + (size_t)grow * 512 + kk * 32);
#pragma unroll
        for (int i = 0; i < 8; ++i) wreg[i] = wr[i];
    } else {
        const uint2* wr = (const uint2*)((const unsigned short*)Whh_raw + (size_t)grow * 512 + kk * 32);
#pragma unroll
        for (int i = 0; i < 8; ++i) {
            uint2 u = wr[i];
            wreg[i] = make_float4(b2f_lo(u.x), b2f_hi(u.x), b2f_lo(u.y), b2f_hi(u.y));
        }
    }

    for (int i = tid; i < 576; i += 1024) hpad[0][i] = 0.0f;   // h_{-1} = 0
    if (tid == 0) step_flag = 0;
    __syncthreads();

    unsigned* hview = (unsigned*)h_hist;
    float c = 0.0f;

    for (int t = 0; t < 4096; ++t) {
        // h-independent: issue before the wait so latency hides under the spin
        float xv = __bfloat162float(xp2[(size_t)t * 2048 + grow]);

        // wait for hpad[t&1] = h_{t-1}  (LDS spin, no fabric traffic)
        unsigned ls = 0;
        while (__hip_atomic_load(&step_flag, __ATOMIC_ACQUIRE,
                                 __HIP_MEMORY_SCOPE_WORKGROUP) < t) {
            if (++ls > (1u << 24)) break;   // anti-hang
        }

        const float4* h4 = (const float4*)(&hpad[t & 1][kk * 36]);
        float acc = 0.0f;
#pragma unroll
        for (int i = 0; i < 8; ++i) {
            float4 hv = h4[i];
            acc += wreg[i].x * hv.x + wreg[i].y * hv.y +
                   wreg[i].z * hv.z + wreg[i].w * hv.w;
        }
        acc += __shfl_xor(acc, 1);
        acc += __shfl_xor(acc, 2);
        acc += __shfl_xor(acc, 4);
        acc += __shfl_xor(acc, 8);
        float gvt = acc + xv;

        float iv = __shfl(gvt, kk);
        float fv = __shfl(gvt, 16 + kk);
        float gg = __shfl(gvt, 32 + kk);
        float ov = __shfl(gvt, 48 + kk);
        c = sigf(fv) * c + sigf(iv) * tanh_f(gg);
        float h = sigf(ov) * tanh_f(c);

        if (lane == 0) hout[wave] = h;
        __syncthreads();                 // hout complete; hpad[t&1] reads done

        if (wave == 0) {
            // ONE coalesced 64B transaction for this WG's whole h-line
            if (lane < 16)
                __hip_atomic_store(hview + (size_t)t * 512 + wg * 16 + lane,
                                   __float_as_uint(hout[lane]),
                                   __ATOMIC_RELAXED, __HIP_MEMORY_SCOPE_AGENT);

            if (t < 4095) {
                unsigned v[8];
                if ((lane >> 1) == wg) {
                    // own line: take from LDS, skip fabric
#pragma unroll
                    for (int i = 0; i < 8; ++i)
                        v[i] = __float_as_uint(hout[(lane & 1) * 8 + i]);
                } else {
                    const unsigned* src = hview + (size_t)t * 512 + lane * 8;
                    unsigned spins = 0;
                    bool bail = false;
                    for (;;) {
#pragma unroll
                        for (int i = 0; i < 8; ++i)
                            v[i] = __hip_atomic_load(src + i, __ATOMIC_RELAXED,
                                                     __HIP_MEMORY_SCOPE_AGENT);
                        int ok = 1;
#pragma unroll
                        for (int i = 0; i < 8; ++i) ok &= (v[i] != SENT);
                        // note: __all() over the wave would hang (own-line lanes
                        // exited); per-lane loop exit instead
                        if (ok) break;
                        if (++spins > (1u << 22)) { bail = true; break; }
                    }
                    if (bail) {
#pragma unroll
                        for (int i = 0; i < 8; ++i) v[i] = __float_as_uint(12345.0f);
                    }
                }
                // dword d=lane*8+i -> hpad chunk d>>5, stride 36
                float* dst = &hpad[(t + 1) & 1][(lane >> 2) * 36 + (lane & 3) * 8];
                ((float4*)dst)[0] = make_float4(__uint_as_float(v[0]), __uint_as_float(v[1]),
                                                __uint_as_float(v[2]), __uint_as_float(v[3]));
                ((float4*)dst)[1] = make_float4(__uint_as_float(v[4]), __uint_as_float(v[5]),
                                                __uint_as_float(v[6]), __uint_as_float(v[7]));
                __hip_atomic_store(&step_flag, t + 1, __ATOMIC_RELEASE,
                                   __HIP_MEMORY_SCOPE_WORKGROUP);
            }
        }
    }
}

// ---- K6: logits + log_softmax --------------------------------------------
__global__ void __launch_bounds__(64) out_kernel(
    const float* __restrict__ h_hist, const float* __restrict__ W1T,
    const void* __restrict__ b1raw, void* __restrict__ out,
    const int* __restrict__ flagp)
{
    __shared__ float hb[512];
    int flag = flagp[0];
    int t = blockIdx.x, j = threadIdx.x;
    const float4* src = (const float4*)(h_hist + (size_t)t * 512);
    ((float4*)hb)[j * 2] = src[j * 2];
    ((float4*)hb)[j * 2 + 1] = src[j * 2 + 1];
    __syncthreads();

    float acc = flag ? __bfloat162float(((const __hip_bfloat16*)b1raw)[j])
                     : ((const float*)b1raw)[j];
#pragma unroll 8
    for (int k = 0; k < 512; ++k)
        acc += hb[k] * W1T[k * 64 + j];

    float m = acc;
#pragma unroll
    for (int o = 32; o; o >>= 1) m = fmaxf(m, __shfl_xor(m, o));
    float e = __expf(acc - m);
    float s = e;
#pragma unroll
    for (int o = 32; o; o >>= 1) s += __shfl_xor(s, o);
    float r = acc - m - __logf(s);
    if (flag) ((__hip_bfloat16*)out)[t * 64 + j] = __float2bfloat16(r);
    else      ((float*)out)[t * 64 + j] = r;
}

extern "C" void kernel_launch(void* const* d_in, const int* in_sizes, int n_in,
                              void* d_out, int out_size, void* d_ws, size_t ws_size,
                              hipStream_t stream)
{
    (void)in_sizes; (void)n_in; (void)out_size; (void)ws_size;
    const void* char_emb = d_in[0];
    const void* char_Wih = d_in[1];
    const void* char_Whh = d_in[2];
    const void* char_bih = d_in[3];
    const void* char_bhh = d_in[4];
    const void* word_emb = d_in[5];
    const void* Wih      = d_in[6];
    const void* Whh      = d_in[7];
    const void* bih      = d_in[8];
    const void* bhh      = d_in[9];
    const void* W1       = d_in[10];
    const void* b1       = d_in[11];
    const int* x     = (const int*)d_in[12];
    const int* chars = (const int*)d_in[13];
    const int* lens  = (const int*)d_in[14];

    float* ws    = (float*)d_ws;
    int*   flagp = (int*)(ws + OFF_FLAG);
    float* cembf = ws + OFF_CEMB;
    float* cWihf = ws + OFF_CWIH;
    float* cbihf = ws + OFF_CBIH;
    float* cbhhf = ws + OFF_CBHH;
    float* cWhhf = ws + OFF_CWHH;
    float* bihf  = ws + OFF_BIH;
    float* bhhf  = ws + OFF_BHH;
    float* W1T   = ws + OFF_W1T;
    float* cge   = ws + OFF_CGE;
    float* charh = ws + OFF_CH;
    __hip_bfloat16* xp2 = (__hip_bfloat16*)(ws + OFF_XP2);
    float* hh    = ws + OFF_HH;

    hipMemsetAsync(hh, 0xFF, (size_t)4096 * 512 * 4, stream);

    detect_kernel<<<1, 64, 0, stream>>>((const unsigned*)char_emb, flagp);

    convf_kernel<<<(8192 + 255) / 256, 256, 0, stream>>>(char_emb, cembf, 8192, flagp);
    convf_kernel<<<(32768 + 255) / 256, 256, 0, stream>>>(char_Wih, cWihf, 32768, flagp);
    convf_kernel<<<2, 256, 0, stream>>>(char_bih, cbihf, 512, flagp);
    convf_kernel<<<2, 256, 0, stream>>>(char_bhh, cbhhf, 512, flagp);
    convf_kernel<<<(65536 + 255) / 256, 256, 0, stream>>>(char_Whh, cWhhf, 65536, flagp);
    convf_kernel<<<8, 256, 0, stream>>>(bih, bihf, 2048, flagp);
    convf_kernel<<<8, 256, 0, stream>>>(bhh, bhhf, 2048, flagp);
    w1t_kernel<<<128, 256, 0, stream>>>(W1, W1T, flagp);

    cge_kernel<<<128, 256, 0, stream>>>(cembf, cWihf, cbihf, cbhhf, cge);
    char_lstm_kernel<<<256, 256, 0, stream>>>(cge, cWhhf, chars, lens, charh);
    xp2_kernel<<<256, 256, 0, stream>>>(word_emb, x, charh, Wih, bihf, bhhf, xp2, flagp);
    word_lstm_kernel<<<32, 1024, 0, stream>>>(xp2, Whh, hh, flagp);
    out_kernel<<<4096, 64, 0, stream>>>(hh, W1T, b1, d_out, flagp);
}